// Round 1
// baseline (377.546 us; speedup 1.0000x reference)
//
#include <hip/hip_runtime.h>

#define HH  1024
#define WW  1024
#define HID 256

typedef __attribute__((ext_vector_type(4))) float f32x4;
typedef __attribute__((ext_vector_type(8))) short short8;

static __device__ __forceinline__ unsigned short f2bf(float x) {
    unsigned u = __builtin_bit_cast(unsigned, x);
    u = (u + 0x7fffu + ((u >> 16) & 1u)) >> 16;   // RNE
    return (unsigned short)u;
}

// ---------------- stage 1: per-axis branch MLPs ----------------

// transpose pw1/pw2 (256x256) so layer_k weight reads are coalesced
__global__ __launch_bounds__(256) void transpose_k(
    const float* __restrict__ pw1, const float* __restrict__ pw2,
    float* __restrict__ pw1t, float* __restrict__ pw2t)
{
    __shared__ float tile[32][33];
    const float* src = blockIdx.z ? pw2 : pw1;
    float*       dst = blockIdx.z ? pw2t : pw1t;
    const int bx = blockIdx.x * 32, by = blockIdx.y * 32;
    const int tx = threadIdx.x & 31, ty0 = threadIdx.x >> 5;   // 32x8
    #pragma unroll
    for (int r = 0; r < 32; r += 8)
        tile[ty0 + r][tx] = src[(by + ty0 + r) * HID + bx + tx];
    __syncthreads();
    #pragma unroll
    for (int r = 0; r < 32; r += 8)
        dst[(bx + ty0 + r) * HID + by + tx] = tile[tx][ty0 + r];
}

// s0[g][t] = sin(coord[g] * bw[t] + bb[t]), g in [0,2048): 0..1023 = x-axis, 1024.. = y-axis
__global__ __launch_bounds__(256) void branch_k(
    const float* __restrict__ x, const float* __restrict__ y,
    const float* __restrict__ bw0, const float* __restrict__ bb0,
    const float* __restrict__ bw1, const float* __restrict__ bb1,
    float* __restrict__ s0)
{
    const int t  = threadIdx.x;
    const int g0 = blockIdx.x * 8;          // 8 rows/block, axis-uniform
    const int axis = g0 >> 10;
    const float* coord = axis ? y : x;
    const float* bw = axis ? bw1 : bw0;
    const float* bb = axis ? bb1 : bb0;
    const int base = g0 & 1023;
    const float wv = bw[t], bv = bb[t];
    #pragma unroll
    for (int q = 0; q < 8; ++q)
        s0[(g0 + q) * HID + t] = __sinf(coord[base + q] * wv + bv);
}

// sout = sin(sin_in @ Wt + b); final layer splits into fx (bf16) / fy (f32)
__global__ __launch_bounds__(256) void layer_k(
    const float* __restrict__ sin_in,
    const float* __restrict__ wt,       // transposed weights [c][o]
    const float* __restrict__ bias,
    float* __restrict__ sout,
    unsigned short* __restrict__ fx_b, float* __restrict__ fy_f,
    const int is_final)
{
    const int t  = threadIdx.x;
    const int g0 = blockIdx.x * 8;
    float acc[8];
    const float bv = bias[t];
    #pragma unroll
    for (int q = 0; q < 8; ++q) acc[q] = bv;
    const float* srow = sin_in + g0 * HID;  // wave-uniform -> scalar loads
    for (int c = 0; c < HID; ++c) {
        const float wv = wt[c * HID + t];   // coalesced
        #pragma unroll
        for (int q = 0; q < 8; ++q) acc[q] += srow[q * HID + c] * wv;
    }
    if (!is_final) {
        #pragma unroll
        for (int q = 0; q < 8; ++q) sout[(g0 + q) * HID + t] = __sinf(acc[q]);
    } else {
        #pragma unroll
        for (int q = 0; q < 8; ++q) {
            const float h = __sinf(acc[q]);
            const int g = g0 + q;
            if (g < HH) fx_b[g * HID + t] = f2bf(h);
            else        fy_f[(g - HH) * HID + t] = h;
        }
    }
}

// ---------------- stage 2: fused outer-product + MLP head ----------------
// One block per j (y/W index). 4 waves; wave w owns hidden slice n in [64w,64w+64).
// A' = qw1 (.) fy[j]  held as bf16 MFMA A-fragments in registers (32 frags = 128 VGPR).
// Stream fx i-tiles (16 rows) as B-fragments from global (L1/L2-resident).
// D[n][i]: col = lane&15 = i_local, row = (lane>>4)*4 + reg = n_local (m89 layout).
__global__ __launch_bounds__(256, 2) void fused_k(
    const float* __restrict__ qw1, const float* __restrict__ qb1,
    const float* __restrict__ qw2, const float* __restrict__ qb2,
    const unsigned short* __restrict__ fx_b, const float* __restrict__ fy_f,
    float* __restrict__ out)
{
    const int j   = blockIdx.x;
    const int tid = threadIdx.x;
    const int l   = tid & 63;
    const int w   = tid >> 6;        // wave 0..3
    const int n0  = w * 64;
    const int il  = l & 15;
    const int lg  = l >> 4;          // 0..3

    // per-thread slices of qb1 / qw2 for the C/D rows this lane owns
    float qb1r[4][4], qw2r[3][4][4];
    #pragma unroll
    for (int nt = 0; nt < 4; ++nt) {
        #pragma unroll
        for (int r = 0; r < 4; ++r) {
            const int n = n0 + nt * 16 + lg * 4 + r;
            qb1r[nt][r]    = qb1[n];
            qw2r[0][nt][r] = qw2[0 * HID + n];
            qw2r[1][nt][r] = qw2[1 * HID + n];
            qw2r[2][nt][r] = qw2[2 * HID + n];
        }
    }
    const float qb2v0 = qb2[0], qb2v1 = qb2[1], qb2v2 = qb2[2];

    // Build A' fragments: lane l holds A'[n0+nt*16+(l&15)][kt*32+lg*8 + 0..7]
    short8 afrag[4][8];
    #pragma unroll
    for (int kt = 0; kt < 8; ++kt) {
        const int kb = kt * 32 + lg * 8;
        const f32x4 fA = *(const f32x4*)&fy_f[j * HID + kb];
        const f32x4 fB = *(const f32x4*)&fy_f[j * HID + kb + 4];
        #pragma unroll
        for (int nt = 0; nt < 4; ++nt) {
            const int n = n0 + nt * 16 + il;
            const f32x4 qA = *(const f32x4*)&qw1[n * HID + kb];
            const f32x4 qB = *(const f32x4*)&qw1[n * HID + kb + 4];
            short8 f;
            f[0] = (short)f2bf(qA[0] * fA[0]);
            f[1] = (short)f2bf(qA[1] * fA[1]);
            f[2] = (short)f2bf(qA[2] * fA[2]);
            f[3] = (short)f2bf(qA[3] * fA[3]);
            f[4] = (short)f2bf(qB[0] * fB[0]);
            f[5] = (short)f2bf(qB[1] * fB[1]);
            f[6] = (short)f2bf(qB[2] * fB[2]);
            f[7] = (short)f2bf(qB[3] * fB[3]);
            afrag[nt][kt] = f;
        }
    }

    __shared__ float red[2][4][3][16];   // [buf][wave][c][i_local]

    for (int it = 0; it < 64; ++it) {
        const int i0 = it * 16;
        f32x4 acc[4];
        #pragma unroll
        for (int nt = 0; nt < 4; ++nt) {
            acc[nt][0] = qb1r[nt][0]; acc[nt][1] = qb1r[nt][1];
            acc[nt][2] = qb1r[nt][2]; acc[nt][3] = qb1r[nt][3];
        }
        // B frags: lane l holds fx[i0+(l&15)][kt*32+lg*8 + 0..7]
        const unsigned short* fxrow = fx_b + (i0 + il) * HID + lg * 8;
        #pragma unroll
        for (int g = 0; g < 2; ++g) {
            short8 bfrag[4];
            #pragma unroll
            for (int kk = 0; kk < 4; ++kk)
                bfrag[kk] = *(const short8*)(fxrow + (g * 4 + kk) * 32);
            #pragma unroll
            for (int kk = 0; kk < 4; ++kk) {
                #pragma unroll
                for (int nt = 0; nt < 4; ++nt)
                    acc[nt] = __builtin_amdgcn_mfma_f32_16x16x32_bf16(
                        afrag[nt][g * 4 + kk], bfrag[kk], acc[nt], 0, 0, 0);
            }
        }
        // epilogue: sin -> 3-channel dot -> cross-lane/wave reduce -> sigmoid
        float p0 = 0.f, p1 = 0.f, p2 = 0.f;
        #pragma unroll
        for (int nt = 0; nt < 4; ++nt) {
            #pragma unroll
            for (int r = 0; r < 4; ++r) {
                const float s = __sinf(acc[nt][r]);
                p0 += qw2r[0][nt][r] * s;
                p1 += qw2r[1][nt][r] * s;
                p2 += qw2r[2][nt][r] * s;
            }
        }
        p0 += __shfl_xor(p0, 16); p0 += __shfl_xor(p0, 32);
        p1 += __shfl_xor(p1, 16); p1 += __shfl_xor(p1, 32);
        p2 += __shfl_xor(p2, 16); p2 += __shfl_xor(p2, 32);
        const int buf = it & 1;
        if (l < 16) {
            red[buf][w][0][l] = p0;
            red[buf][w][1][l] = p1;
            red[buf][w][2][l] = p2;
        }
        __syncthreads();
        if (tid < 48) {
            const int c = tid >> 4, ii = tid & 15;
            const float v = red[buf][0][c][ii] + red[buf][1][c][ii]
                          + red[buf][2][c][ii] + red[buf][3][c][ii]
                          + (c == 0 ? qb2v0 : (c == 1 ? qb2v1 : qb2v2));
            out[c * (WW * HH) + j * HH + i0 + ii] = 1.0f / (1.0f + __expf(-v));
        }
    }
}

extern "C" void kernel_launch(void* const* d_in, const int* in_sizes, int n_in,
                              void* d_out, int out_size, void* d_ws, size_t ws_size,
                              hipStream_t stream)
{
    const float* x   = (const float*)d_in[0];
    const float* y   = (const float*)d_in[1];
    const float* bw0 = (const float*)d_in[2];
    const float* bb0 = (const float*)d_in[3];
    const float* bw1 = (const float*)d_in[4];
    const float* bb1 = (const float*)d_in[5];
    const float* pw1 = (const float*)d_in[6];
    const float* pb1 = (const float*)d_in[7];
    const float* pw2 = (const float*)d_in[8];
    const float* pb2 = (const float*)d_in[9];
    const float* qw1 = (const float*)d_in[10];
    const float* qb1 = (const float*)d_in[11];
    const float* qw2 = (const float*)d_in[12];
    const float* qb2 = (const float*)d_in[13];

    char* ws = (char*)d_ws;
    unsigned short* fx_b = (unsigned short*)(ws);                 // 512 KB
    float* fy_f = (float*)(ws + (512 << 10));                     // 1 MB
    float* pw1t = (float*)(ws + (1536 << 10));                    // 256 KB
    float* pw2t = (float*)(ws + (1792 << 10));                    // 256 KB
    float* s0   = (float*)(ws + (2048 << 10));                    // 2 MB
    float* s1   = (float*)(ws + (4096 << 10));                    // 2 MB
    float* out  = (float*)d_out;

    transpose_k<<<dim3(8, 8, 2), 256, 0, stream>>>(pw1, pw2, pw1t, pw2t);
    branch_k<<<256, 256, 0, stream>>>(x, y, bw0, bb0, bw1, bb1, s0);
    layer_k<<<256, 256, 0, stream>>>(s0, pw1t, pb1, s1, nullptr, nullptr, 0);
    layer_k<<<256, 256, 0, stream>>>(s1, pw2t, pb2, nullptr, fx_b, fy_f, 1);
    fused_k<<<WW, 256, 0, stream>>>(qw1, qb1, qw2, qb2, fx_b, fy_f, out);
}

// Round 2
// 333.872 us; speedup vs baseline: 1.1308x; 1.1308x over previous
//
#include <hip/hip_runtime.h>

#define HH  1024
#define WW  1024
#define HID 256

typedef __attribute__((ext_vector_type(4))) float f32x4;
typedef __attribute__((ext_vector_type(8))) short short8;

static __device__ __forceinline__ unsigned short f2bf(float x) {
    unsigned u = __builtin_bit_cast(unsigned, x);
    u = (u + 0x7fffu + ((u >> 16) & 1u)) >> 16;   // RNE
    return (unsigned short)u;
}

// ---------------- stage 1: per-axis branch MLPs ----------------

__global__ __launch_bounds__(256) void transpose_k(
    const float* __restrict__ pw1, const float* __restrict__ pw2,
    float* __restrict__ pw1t, float* __restrict__ pw2t)
{
    __shared__ float tile[32][33];
    const float* src = blockIdx.z ? pw2 : pw1;
    float*       dst = blockIdx.z ? pw2t : pw1t;
    const int bx = blockIdx.x * 32, by = blockIdx.y * 32;
    const int tx = threadIdx.x & 31, ty0 = threadIdx.x >> 5;   // 32x8
    #pragma unroll
    for (int r = 0; r < 32; r += 8)
        tile[ty0 + r][tx] = src[(by + ty0 + r) * HID + bx + tx];
    __syncthreads();
    #pragma unroll
    for (int r = 0; r < 32; r += 8)
        dst[(bx + ty0 + r) * HID + by + tx] = tile[tx][ty0 + r];
}

__global__ __launch_bounds__(256) void branch_k(
    const float* __restrict__ x, const float* __restrict__ y,
    const float* __restrict__ bw0, const float* __restrict__ bb0,
    const float* __restrict__ bw1, const float* __restrict__ bb1,
    float* __restrict__ s0)
{
    const int t  = threadIdx.x;
    const int g0 = blockIdx.x * 8;          // 8 rows/block, axis-uniform
    const int axis = g0 >> 10;
    const float* coord = axis ? y : x;
    const float* bw = axis ? bw1 : bw0;
    const float* bb = axis ? bb1 : bb0;
    const int base = g0 & 1023;
    const float wv = bw[t], bv = bb[t];
    #pragma unroll
    for (int q = 0; q < 8; ++q)
        s0[(g0 + q) * HID + t] = __sinf(coord[base + q] * wv + bv);
}

__global__ __launch_bounds__(256) void layer_k(
    const float* __restrict__ sin_in,
    const float* __restrict__ wt,       // transposed weights [c][o]
    const float* __restrict__ bias,
    float* __restrict__ sout,
    unsigned short* __restrict__ fx_b, float* __restrict__ fy_f,
    const int is_final)
{
    const int t  = threadIdx.x;
    const int g0 = blockIdx.x * 8;
    float acc[8];
    const float bv = bias[t];
    #pragma unroll
    for (int q = 0; q < 8; ++q) acc[q] = bv;
    const float* srow = sin_in + g0 * HID;  // wave-uniform -> scalar loads
    for (int c = 0; c < HID; ++c) {
        const float wv = wt[c * HID + t];   // coalesced
        #pragma unroll
        for (int q = 0; q < 8; ++q) acc[q] += srow[q * HID + c] * wv;
    }
    if (!is_final) {
        #pragma unroll
        for (int q = 0; q < 8; ++q) sout[(g0 + q) * HID + t] = __sinf(acc[q]);
    } else {
        #pragma unroll
        for (int q = 0; q < 8; ++q) {
            const float h = __sinf(acc[q]);
            const int g = g0 + q;
            if (g < HH) fx_b[g * HID + t] = f2bf(h);
            else        fy_f[(g - HH) * HID + t] = h;
        }
    }
}

// ---------------- stage 2: fused outer-product + MLP head ----------------
// One block per j. 4 waves; wave w owns hidden slice n in [64w,64w+64).
// A' = qw1 (.) fy[j] held as bf16 MFMA A-fragments in registers.
// No barrier in the steady state: per-wave partials go to private LDS strips,
// flushed once per 16 i-tiles (double-buffered -> 4 barriers total).
__global__ __launch_bounds__(256, 2) void fused_k(
    const float* __restrict__ qw1, const float* __restrict__ qb1,
    const float* __restrict__ qw2, const float* __restrict__ qb2,
    const unsigned short* __restrict__ fx_b, const float* __restrict__ fy_f,
    float* __restrict__ out)
{
    const int j   = blockIdx.x;
    const int tid = threadIdx.x;
    const int l   = tid & 63;
    const int w   = tid >> 6;        // wave 0..3
    const int n0  = w * 64;
    const int il  = l & 15;
    const int lg  = l >> 4;          // 0..3

    // per-thread slices of qb1 / qw2 for the C/D rows this lane owns
    float qb1r[4][4], qw2r[3][4][4];
    #pragma unroll
    for (int nt = 0; nt < 4; ++nt) {
        #pragma unroll
        for (int r = 0; r < 4; ++r) {
            const int n = n0 + nt * 16 + lg * 4 + r;
            qb1r[nt][r]    = qb1[n];
            qw2r[0][nt][r] = qw2[0 * HID + n];
            qw2r[1][nt][r] = qw2[1 * HID + n];
            qw2r[2][nt][r] = qw2[2 * HID + n];
        }
    }
    const float qb2v0 = qb2[0], qb2v1 = qb2[1], qb2v2 = qb2[2];

    // Build A' fragments: lane l holds A'[n0+nt*16+(l&15)][kt*32+lg*8 + 0..7]
    short8 afrag[4][8];
    #pragma unroll
    for (int kt = 0; kt < 8; ++kt) {
        const int kb = kt * 32 + lg * 8;
        const f32x4 fA = *(const f32x4*)&fy_f[j * HID + kb];
        const f32x4 fB = *(const f32x4*)&fy_f[j * HID + kb + 4];
        #pragma unroll
        for (int nt = 0; nt < 4; ++nt) {
            const int n = n0 + nt * 16 + il;
            const f32x4 qA = *(const f32x4*)&qw1[n * HID + kb];
            const f32x4 qB = *(const f32x4*)&qw1[n * HID + kb + 4];
            short8 f;
            f[0] = (short)f2bf(qA[0] * fA[0]);
            f[1] = (short)f2bf(qA[1] * fA[1]);
            f[2] = (short)f2bf(qA[2] * fA[2]);
            f[3] = (short)f2bf(qA[3] * fA[3]);
            f[4] = (short)f2bf(qB[0] * fB[0]);
            f[5] = (short)f2bf(qB[1] * fB[1]);
            f[6] = (short)f2bf(qB[2] * fB[2]);
            f[7] = (short)f2bf(qB[3] * fB[3]);
            afrag[nt][kt] = f;
        }
    }

    // per-wave partial strips, double-buffered across 16-iteration segments
    __shared__ float red[2][4][3][256];   // [buf][wave][c][i_chunk]  24 KB

    for (int seg = 0; seg < 4; ++seg) {
        const int buf = seg & 1;
        #pragma unroll 2
        for (int it16 = 0; it16 < 16; ++it16) {
            const int i0 = (seg * 16 + it16) * 16;
            f32x4 acc[4];
            #pragma unroll
            for (int nt = 0; nt < 4; ++nt) {
                acc[nt][0] = qb1r[nt][0]; acc[nt][1] = qb1r[nt][1];
                acc[nt][2] = qb1r[nt][2]; acc[nt][3] = qb1r[nt][3];
            }
            // B frags: lane l holds fx[i0+(l&15)][kt*32+lg*8 + 0..7]
            const unsigned short* fxrow = fx_b + (i0 + il) * HID + lg * 8;
            #pragma unroll
            for (int g = 0; g < 2; ++g) {
                short8 bfrag[4];
                #pragma unroll
                for (int kk = 0; kk < 4; ++kk)
                    bfrag[kk] = *(const short8*)(fxrow + (g * 4 + kk) * 32);
                #pragma unroll
                for (int kk = 0; kk < 4; ++kk) {
                    #pragma unroll
                    for (int nt = 0; nt < 4; ++nt)
                        acc[nt] = __builtin_amdgcn_mfma_f32_16x16x32_bf16(
                            afrag[nt][g * 4 + kk], bfrag[kk], acc[nt], 0, 0, 0);
                }
            }
            // epilogue: sin -> 3-channel dot -> intra-wave reduce -> LDS strip
            float p0 = 0.f, p1 = 0.f, p2 = 0.f;
            #pragma unroll
            for (int nt = 0; nt < 4; ++nt) {
                #pragma unroll
                for (int r = 0; r < 4; ++r) {
                    const float s = __sinf(acc[nt][r]);
                    p0 += qw2r[0][nt][r] * s;
                    p1 += qw2r[1][nt][r] * s;
                    p2 += qw2r[2][nt][r] * s;
                }
            }
            p0 += __shfl_xor(p0, 16); p0 += __shfl_xor(p0, 32);
            p1 += __shfl_xor(p1, 16); p1 += __shfl_xor(p1, 32);
            p2 += __shfl_xor(p2, 16); p2 += __shfl_xor(p2, 32);
            if (l < 16) {
                const int ic = it16 * 16 + l;
                red[buf][w][0][ic] = p0;
                red[buf][w][1][ic] = p1;
                red[buf][w][2][ic] = p2;
            }
        }
        __syncthreads();
        // flush: 768 outputs, coalesced; no trailing barrier needed (dbuf)
        {
            const int ib = j * HH + seg * 256 + tid;
            #pragma unroll
            for (int q = 0; q < 3; ++q) {
                const float v = red[buf][0][q][tid] + red[buf][1][q][tid]
                              + red[buf][2][q][tid] + red[buf][3][q][tid]
                              + (q == 0 ? qb2v0 : (q == 1 ? qb2v1 : qb2v2));
                out[q * (WW * HH) + ib] = 1.0f / (1.0f + __expf(-v));
            }
        }
    }
}

extern "C" void kernel_launch(void* const* d_in, const int* in_sizes, int n_in,
                              void* d_out, int out_size, void* d_ws, size_t ws_size,
                              hipStream_t stream)
{
    const float* x   = (const float*)d_in[0];
    const float* y   = (const float*)d_in[1];
    const float* bw0 = (const float*)d_in[2];
    const float* bb0 = (const float*)d_in[3];
    const float* bw1 = (const float*)d_in[4];
    const float* bb1 = (const float*)d_in[5];
    const float* pw1 = (const float*)d_in[6];
    const float* pb1 = (const float*)d_in[7];
    const float* pw2 = (const float*)d_in[8];
    const float* pb2 = (const float*)d_in[9];
    const float* qw1 = (const float*)d_in[10];
    const float* qb1 = (const float*)d_in[11];
    const float* qw2 = (const float*)d_in[12];
    const float* qb2 = (const float*)d_in[13];

    char* ws = (char*)d_ws;
    unsigned short* fx_b = (unsigned short*)(ws);                 // 512 KB
    float* fy_f = (float*)(ws + (512 << 10));                     // 1 MB
    float* pw1t = (float*)(ws + (1536 << 10));                    // 256 KB
    float* pw2t = (float*)(ws + (1792 << 10));                    // 256 KB
    float* s0   = (float*)(ws + (2048 << 10));                    // 2 MB
    float* s1   = (float*)(ws + (4096 << 10));                    // 2 MB
    float* out  = (float*)d_out;

    transpose_k<<<dim3(8, 8, 2), 256, 0, stream>>>(pw1, pw2, pw1t, pw2t);
    branch_k<<<256, 256, 0, stream>>>(x, y, bw0, bb0, bw1, bb1, s0);
    layer_k<<<256, 256, 0, stream>>>(s0, pw1t, pb1, s1, nullptr, nullptr, 0);
    layer_k<<<256, 256, 0, stream>>>(s1, pw2t, pb2, nullptr, fx_b, fy_f, 1);
    fused_k<<<WW, 256, 0, stream>>>(qw1, qb1, qw2, qb2, fx_b, fy_f, out);
}

// Round 3
// 227.582 us; speedup vs baseline: 1.6589x; 1.4670x over previous
//
#include <hip/hip_runtime.h>

#define HH  1024
#define WW  1024
#define HID 256

typedef __attribute__((ext_vector_type(4))) float f32x4;
typedef __attribute__((ext_vector_type(8))) short short8;

static __device__ __forceinline__ unsigned short f2bf(float x) {
    unsigned u = __builtin_bit_cast(unsigned, x);
    u = (u + 0x7fffu + ((u >> 16) & 1u)) >> 16;   // RNE
    return (unsigned short)u;
}

// ---------------- stage 1: per-axis branch MLPs ----------------

__global__ __launch_bounds__(256) void transpose_k(
    const float* __restrict__ pw1, const float* __restrict__ pw2,
    float* __restrict__ pw1t, float* __restrict__ pw2t)
{
    __shared__ float tile[32][33];
    const float* src = blockIdx.z ? pw2 : pw1;
    float*       dst = blockIdx.z ? pw2t : pw1t;
    const int bx = blockIdx.x * 32, by = blockIdx.y * 32;
    const int tx = threadIdx.x & 31, ty0 = threadIdx.x >> 5;   // 32x8
    #pragma unroll
    for (int r = 0; r < 32; r += 8)
        tile[ty0 + r][tx] = src[(by + ty0 + r) * HID + bx + tx];
    __syncthreads();
    #pragma unroll
    for (int r = 0; r < 32; r += 8)
        dst[(bx + ty0 + r) * HID + by + tx] = tile[tx][ty0 + r];
}

__global__ __launch_bounds__(256) void branch_k(
    const float* __restrict__ x, const float* __restrict__ y,
    const float* __restrict__ bw0, const float* __restrict__ bb0,
    const float* __restrict__ bw1, const float* __restrict__ bb1,
    float* __restrict__ s0)
{
    const int t  = threadIdx.x;
    const int g0 = blockIdx.x * 8;          // 8 rows/block, axis-uniform
    const int axis = g0 >> 10;
    const float* coord = axis ? y : x;
    const float* bw = axis ? bw1 : bw0;
    const float* bb = axis ? bb1 : bb0;
    const int base = g0 & 1023;
    const float wv = bw[t], bv = bb[t];
    #pragma unroll
    for (int q = 0; q < 8; ++q)
        s0[(g0 + q) * HID + t] = __sinf(coord[base + q] * wv + bv);
}

__global__ __launch_bounds__(256) void layer_k(
    const float* __restrict__ sin_in,
    const float* __restrict__ wt,       // transposed weights [c][o]
    const float* __restrict__ bias,
    float* __restrict__ sout,
    unsigned short* __restrict__ fx_b, float* __restrict__ fy_f,
    const int is_final)
{
    const int t  = threadIdx.x;
    const int g0 = blockIdx.x * 8;
    float acc[8];
    const float bv = bias[t];
    #pragma unroll
    for (int q = 0; q < 8; ++q) acc[q] = bv;
    const float* srow = sin_in + g0 * HID;  // wave-uniform -> scalar loads
    for (int c = 0; c < HID; ++c) {
        const float wv = wt[c * HID + t];   // coalesced
        #pragma unroll
        for (int q = 0; q < 8; ++q) acc[q] += srow[q * HID + c] * wv;
    }
    if (!is_final) {
        #pragma unroll
        for (int q = 0; q < 8; ++q) sout[(g0 + q) * HID + t] = __sinf(acc[q]);
    } else {
        #pragma unroll
        for (int q = 0; q < 8; ++q) {
            const float h = __sinf(acc[q]);
            const int g = g0 + q;
            if (g < HH) fx_b[g * HID + t] = f2bf(h);
            else        fy_f[(g - HH) * HID + t] = h;
        }
    }
}

// ---------------- stage 2: fused outer-product + MLP head ----------------
// One block per j. 4 waves; wave w owns hidden slice n in [64w,64w+64).
// A' = qw1 (.) fy[j] held as bf16 MFMA A-fragments in registers.
// fx i-tiles (16 rows x 512 B = 8 KB) staged into LDS via global_load_lds
// (linear dest, PRE-SWIZZLED global source; reads apply the same XOR ->
// conflict-free ds_read_b128). Double-buffered, one barrier per iteration.
__global__ __launch_bounds__(256, 2) void fused_k(
    const float* __restrict__ qw1, const float* __restrict__ qb1,
    const float* __restrict__ qw2, const float* __restrict__ qb2,
    const unsigned short* __restrict__ fx_b, const float* __restrict__ fy_f,
    float* __restrict__ out)
{
    const int j   = blockIdx.x;
    const int tid = threadIdx.x;
    const int l   = tid & 63;
    const int w   = tid >> 6;        // wave 0..3
    const int n0  = w * 64;
    const int il  = l & 15;
    const int lg  = l >> 4;          // 0..3

    // per-thread slices of qb1 / qw2 for the C/D rows this lane owns
    float qb1r[4][4], qw2r[3][4][4];
    #pragma unroll
    for (int nt = 0; nt < 4; ++nt) {
        #pragma unroll
        for (int r = 0; r < 4; ++r) {
            const int n = n0 + nt * 16 + lg * 4 + r;
            qb1r[nt][r]    = qb1[n];
            qw2r[0][nt][r] = qw2[0 * HID + n];
            qw2r[1][nt][r] = qw2[1 * HID + n];
            qw2r[2][nt][r] = qw2[2 * HID + n];
        }
    }
    const float qb2v0 = qb2[0], qb2v1 = qb2[1], qb2v2 = qb2[2];

    // Build A' fragments: lane l holds A'[n0+nt*16+(l&15)][kt*32+lg*8 + 0..7]
    short8 afrag[4][8];
    #pragma unroll
    for (int kt = 0; kt < 8; ++kt) {
        const int kb = kt * 32 + lg * 8;
        const f32x4 fA = *(const f32x4*)&fy_f[j * HID + kb];
        const f32x4 fB = *(const f32x4*)&fy_f[j * HID + kb + 4];
        #pragma unroll
        for (int nt = 0; nt < 4; ++nt) {
            const int n = n0 + nt * 16 + il;
            const f32x4 qA = *(const f32x4*)&qw1[n * HID + kb];
            const f32x4 qB = *(const f32x4*)&qw1[n * HID + kb + 4];
            short8 f;
            f[0] = (short)f2bf(qA[0] * fA[0]);
            f[1] = (short)f2bf(qA[1] * fA[1]);
            f[2] = (short)f2bf(qA[2] * fA[2]);
            f[3] = (short)f2bf(qA[3] * fA[3]);
            f[4] = (short)f2bf(qB[0] * fB[0]);
            f[5] = (short)f2bf(qB[1] * fB[1]);
            f[6] = (short)f2bf(qB[2] * fB[2]);
            f[7] = (short)f2bf(qB[3] * fB[3]);
            afrag[nt][kt] = f;
        }
    }

    __shared__ __attribute__((aligned(16))) char tile[2][8192]; // fx i-tile dbuf
    __shared__ float red[2][4][3][256];                         // partial strips

    // staging: per-lane swizzled global source offset (within 8 KB tile).
    // instr r of wave w covers linear LDS bytes [w*2048 + r*1024 + lane*16).
    unsigned swz[2];
    #pragma unroll
    for (int r = 0; r < 2; ++r) {
        const unsigned o   = w * 2048 + r * 1024 + l * 16;
        const unsigned row = o >> 9, col = o & 511;
        swz[r] = row * 512 + (col ^ ((row & 7) << 4));
    }
    const char* fxb = (const char*)fx_b;

    // ds_read byte addresses (within tile) for kk=0..3; kk+4 is +256 bytes
    unsigned rda[4];
    #pragma unroll
    for (int kk = 0; kk < 4; ++kk) {
        const unsigned col = lg * 16 + kk * 64;
        rda[kk] = il * 512 + (col ^ ((il & 7) << 4));
    }

    // prologue: stage tile 0 into buf 0
    #pragma unroll
    for (int r = 0; r < 2; ++r)
        __builtin_amdgcn_global_load_lds(
            (const __attribute__((address_space(1))) unsigned*)(fxb + swz[r]),
            (__attribute__((address_space(3))) unsigned*)(&tile[0][w * 2048 + r * 1024]),
            16, 0, 0);
    __syncthreads();

    int itg = 0;
    for (int seg = 0; seg < 4; ++seg) {
        const int sbuf = seg & 1;
        for (int it16 = 0; it16 < 16; ++it16, ++itg) {
            const int buf = itg & 1;
            // stage next tile into buf^1 (completes at this iter's barrier)
            if (itg < 63) {
                const char* src = fxb + (unsigned)(itg + 1) * 8192u;
                #pragma unroll
                for (int r = 0; r < 2; ++r)
                    __builtin_amdgcn_global_load_lds(
                        (const __attribute__((address_space(1))) unsigned*)(src + swz[r]),
                        (__attribute__((address_space(3))) unsigned*)(&tile[buf ^ 1][w * 2048 + r * 1024]),
                        16, 0, 0);
            }
            f32x4 acc[4];
            #pragma unroll
            for (int nt = 0; nt < 4; ++nt) {
                acc[nt][0] = qb1r[nt][0]; acc[nt][1] = qb1r[nt][1];
                acc[nt][2] = qb1r[nt][2]; acc[nt][3] = qb1r[nt][3];
            }
            const char* tb = &tile[buf][0];
            #pragma unroll
            for (int g = 0; g < 2; ++g) {
                short8 bfrag[4];
                #pragma unroll
                for (int kk = 0; kk < 4; ++kk)
                    bfrag[kk] = *(const short8*)(tb + rda[kk] + g * 256);
                #pragma unroll
                for (int kk = 0; kk < 4; ++kk) {
                    #pragma unroll
                    for (int nt = 0; nt < 4; ++nt)
                        acc[nt] = __builtin_amdgcn_mfma_f32_16x16x32_bf16(
                            afrag[nt][g * 4 + kk], bfrag[kk], acc[nt], 0, 0, 0);
                }
            }
            // epilogue: sin -> 3-channel dot -> intra-wave reduce -> LDS strip
            float p0 = 0.f, p1 = 0.f, p2 = 0.f;
            #pragma unroll
            for (int nt = 0; nt < 4; ++nt) {
                #pragma unroll
                for (int r = 0; r < 4; ++r) {
                    const float s = __sinf(acc[nt][r]);
                    p0 += qw2r[0][nt][r] * s;
                    p1 += qw2r[1][nt][r] * s;
                    p2 += qw2r[2][nt][r] * s;
                }
            }
            p0 += __shfl_xor(p0, 16); p0 += __shfl_xor(p0, 32);
            p1 += __shfl_xor(p1, 16); p1 += __shfl_xor(p1, 32);
            p2 += __shfl_xor(p2, 16); p2 += __shfl_xor(p2, 32);
            if (l < 16) {
                const int ic = it16 * 16 + l;
                red[sbuf][w][0][ic] = p0;
                red[sbuf][w][1][ic] = p1;
                red[sbuf][w][2][ic] = p2;
            }
            __syncthreads();   // staging done + red visible + dbuf protection
        }
        // flush: 768 outputs, coalesced; red double-buffer -> no extra barrier
        {
            const int ib = j * HH + seg * 256 + tid;
            #pragma unroll
            for (int q = 0; q < 3; ++q) {
                const float v = red[sbuf][0][q][tid] + red[sbuf][1][q][tid]
                              + red[sbuf][2][q][tid] + red[sbuf][3][q][tid]
                              + (q == 0 ? qb2v0 : (q == 1 ? qb2v1 : qb2v2));
                out[q * (WW * HH) + ib] = 1.0f / (1.0f + __expf(-v));
            }
        }
    }
}

extern "C" void kernel_launch(void* const* d_in, const int* in_sizes, int n_in,
                              void* d_out, int out_size, void* d_ws, size_t ws_size,
                              hipStream_t stream)
{
    const float* x   = (const float*)d_in[0];
    const float* y   = (const float*)d_in[1];
    const float* bw0 = (const float*)d_in[2];
    const float* bb0 = (const float*)d_in[3];
    const float* bw1 = (const float*)d_in[4];
    const float* bb1 = (const float*)d_in[5];
    const float* pw1 = (const float*)d_in[6];
    const float* pb1 = (const float*)d_in[7];
    const float* pw2 = (const float*)d_in[8];
    const float* pb2 = (const float*)d_in[9];
    const float* qw1 = (const float*)d_in[10];
    const float* qb1 = (const float*)d_in[11];
    const float* qw2 = (const float*)d_in[12];
    const float* qb2 = (const float*)d_in[13];

    char* ws = (char*)d_ws;
    unsigned short* fx_b = (unsigned short*)(ws);                 // 512 KB
    float* fy_f = (float*)(ws + (512 << 10));                     // 1 MB
    float* pw1t = (float*)(ws + (1536 << 10));                    // 256 KB
    float* pw2t = (float*)(ws + (1792 << 10));                    // 256 KB
    float* s0   = (float*)(ws + (2048 << 10));                    // 2 MB
    float* s1   = (float*)(ws + (4096 << 10));                    // 2 MB
    float* out  = (float*)d_out;

    transpose_k<<<dim3(8, 8, 2), 256, 0, stream>>>(pw1, pw2, pw1t, pw2t);
    branch_k<<<256, 256, 0, stream>>>(x, y, bw0, bb0, bw1, bb1, s0);
    layer_k<<<256, 256, 0, stream>>>(s0, pw1t, pb1, s1, nullptr, nullptr, 0);
    layer_k<<<256, 256, 0, stream>>>(s1, pw2t, pb2, nullptr, fx_b, fy_f, 1);
    fused_k<<<WW, 256, 0, stream>>>(qw1, qb1, qw2, qb2, fx_b, fy_f, out);
}